// Round 11
// baseline (48.060 us; speedup 1.0000x reference)
//
#include <hip/hip_runtime.h>

// IIR filter bank: B=16, T=32768, F=30, order 6 (K=7).
// Overlap-and-discard chunking (WARM=128 per 64-sample lane chunk).
// R10: f-SEQUENTIAL blocks. R6-R9 converged to ~30us across four different
//   structures; common factor = global writes as 512B-2KB runs at 128KB
//   (power-of-2) stride -> 62MB/29us = 2.1 TB/s effective, vs fills' 6.6.
//   Fix: block = (b, f, 4096-sample span), ONE wave; lane c computes chunk
//   [c*64,+64) after 128 warm steps (x read from global; L2-resident 2MB).
//   Outputs to padded LDS tile (chunk stride 68 floats -> ds ops spread
//   across all 8 b128 bank-groups), then flush 16KB FULLY CONTIGUOUS
//   (1KB sequential per store instruction). 3840 blocks x 17KB LDS ->
//   9 blocks/CU, ~2.25 waves/SIMD.

#define BB 16
#define TT 32768
#define FF 30
#define KK 7
#define ORD 6
#define LCH 64                 // samples per lane
#define WARM 128
#define SPAN (64 * LCH)        // 4096 samples per block
#define NSP (TT / SPAN)        // 8 spans per row
#define CSTR 68                // padded lane-chunk stride (272B, 16B-aligned)
#define BLK 64                 // one wave

// Transposed direct-form II step: 13 FMAs, no state shifting.
__device__ __forceinline__ float iir_step(float xv, float st[ORD],
                                          const float bcf[KK],
                                          const float acf[ORD]) {
    float y = fmaf(bcf[0], xv, st[0]);
#pragma unroll
    for (int j = 0; j < ORD - 1; ++j)
        st[j] = fmaf(-acf[j], y, fmaf(bcf[j + 1], xv, st[j + 1]));
    st[ORD - 1] = fmaf(-acf[ORD - 1], y, bcf[KK - 1] * xv);
    return y;
}

__global__ __launch_bounds__(BLK) void iir_seq_kernel(
    const float* __restrict__ x,    // [B][T]
    const float* __restrict__ bs,   // [F][K]
    const float* __restrict__ as_,  // [F][K]
    float* __restrict__ out)        // [B][F][T]
{
    __shared__ __align__(16) float ly[BLK * CSTR];   // 17408 B

    const int lane = threadIdx.x;
    const int bid  = blockIdx.x;
    const int b  = bid / (FF * NSP);
    const int r  = bid % (FF * NSP);
    const int f  = r / NSP;
    const int sp = r % NSP;
    const int t0 = sp * SPAN;

    // Coefficients are lane-uniform (block owns one f) -> scalar regs.
    const float inv_a0 = 1.0f / as_[f * KK];
    float bcf[KK], acf[ORD];
#pragma unroll
    for (int j = 0; j < KK; ++j) bcf[j] = bs[f * KK + j] * inv_a0;
#pragma unroll
    for (int j = 0; j < ORD; ++j) acf[j] = as_[f * KK + 1 + j] * inv_a0;

    const float* __restrict__ xrow = x + b * TT;
    const int tc   = t0 + lane * LCH;   // this lane's output chunk start
    const int wsrt = tc - WARM;         // <0 only for sp==0, lane<2

    float st[ORD];
#pragma unroll
    for (int j = 0; j < ORD; ++j) st[j] = 0.0f;

    // Warm-up: 128 discarded steps. Zero-fill t<0 (zero input keeps zero
    // state -> exact for the head). wsrt is a multiple of 4: aligned loads.
#pragma unroll 8
    for (int s = 0; s < WARM; s += 4) {
        const int t = wsrt + s;
        float4 v = make_float4(0.f, 0.f, 0.f, 0.f);
        if (t >= 0) v = *reinterpret_cast<const float4*>(xrow + t);
        iir_step(v.x, st, bcf, acf);
        iir_step(v.y, st, bcf, acf);
        iir_step(v.z, st, bcf, acf);
        iir_step(v.w, st, bcf, acf);
    }

    // Output: 64 steps into this lane's padded LDS chunk.
    // ds_write_b128 banks: float4 slot = 17*lane + s/4 -> group (lane+s/4)%8
    // spreads uniformly over all 8 bank-groups.
    float* lyc = ly + lane * CSTR;
#pragma unroll
    for (int s = 0; s < LCH; s += 4) {
        const float4 v = *reinterpret_cast<const float4*>(xrow + tc + s);
        float4 y;
        y.x = iir_step(v.x, st, bcf, acf);
        y.y = iir_step(v.y, st, bcf, acf);
        y.z = iir_step(v.z, st, bcf, acf);
        y.w = iir_step(v.w, st, bcf, acf);
        *reinterpret_cast<float4*>(lyc + s) = y;
    }
    __syncthreads();   // single wave: cheap

    // Flush: 4096 floats = 1024 float4, 16 per lane, in t-order.
    // Each instruction writes 64 consecutive float4 = 1KB sequential;
    // whole block = 16KB contiguous.
    float* __restrict__ obase = out + (b * FF + f) * TT + t0;
#pragma unroll
    for (int it = 0; it < (SPAN / 4) / BLK; ++it) {   // 16
        const int p = it * BLK + lane;   // float4 index within span
        const int c = p >> 4;            // source lane-chunk
        const int k = p & 15;            // float4 within chunk
        const float4 v =
            *reinterpret_cast<const float4*>(ly + c * CSTR + 4 * k);
        *reinterpret_cast<float4*>(obase + 4 * p) = v;
    }
}

extern "C" void kernel_launch(void* const* d_in, const int* in_sizes, int n_in,
                              void* d_out, int out_size, void* d_ws,
                              size_t ws_size, hipStream_t stream) {
    const float* x   = (const float*)d_in[0];
    const float* bs  = (const float*)d_in[1];
    const float* as_ = (const float*)d_in[2];
    float* out = (float*)d_out;

    const int grid = BB * FF * NSP;  // 3840 single-wave blocks
    hipLaunchKernelGGL(iir_seq_kernel, dim3(grid), dim3(BLK), 0, stream,
                       x, bs, as_, out);
}

// Round 12
// 36.079 us; speedup vs baseline: 1.3321x; 1.3321x over previous
//
#include <hip/hip_runtime.h>

// IIR filter bank: B=16, T=32768, F=30, order 6 (K=7).
// Overlap-and-discard chunking (WARM=128 per 64-sample lane chunk; trunc
// 0.95^128 ~ 1.4e-3 * state, absmax stays 2.0 = FP noise).
// R11: f-sequential blocks (contiguous 16KB writes, R10) + LDS-staged x
//   (fixes R10's per-lane strided loads: 48 instr x 64 cache lines each
//   ~ 12us/CU of L1 serialization -> 17 coalesced float4 instr).
//   x tile skewed: sample 64q+r at lds[65q+r] (1 pad float / 64) ->
//   all compute-phase scalar LDS ops hit banks (lane+r)%32 = 2-way = free.
//   Lane c: warm groups q=c,c+1; output group q=c+2 overwritten IN PLACE
//   (group private to lane in output phase); flush contiguous.
//   LDS 17.2KB -> 9 single-wave blocks/CU at independent phases.

#define BB 16
#define TT 32768
#define FF 30
#define KK 7
#define ORD 6
#define LCH 64                  // output samples per lane
#define WARM 128                // 2 groups of 64
#define SPAN (64 * LCH)         // 4096 samples per block
#define NSP (TT / SPAN)         // 8 spans per (b,f) row
#define NQ ((SPAN + WARM) / 64) // 66 groups in tile
#define NP4 ((SPAN + WARM) / 4) // 1056 float4 to stage
#define BLK 64                  // one wave

// Transposed direct-form II step: 13 FMAs, no state shifting.
__device__ __forceinline__ float iir_step(float xv, float st[ORD],
                                          const float bcf[KK],
                                          const float acf[ORD]) {
    float y = fmaf(bcf[0], xv, st[0]);
#pragma unroll
    for (int j = 0; j < ORD - 1; ++j)
        st[j] = fmaf(-acf[j], y, fmaf(bcf[j + 1], xv, st[j + 1]));
    st[ORD - 1] = fmaf(-acf[ORD - 1], y, bcf[KK - 1] * xv);
    return y;
}

__global__ __launch_bounds__(BLK) void iir_skew_kernel(
    const float* __restrict__ x,    // [B][T]
    const float* __restrict__ bs,   // [F][K]
    const float* __restrict__ as_,  // [F][K]
    float* __restrict__ out)        // [B][F][T]
{
    __shared__ float lx[65 * NQ];   // 4290 floats = 17160 B, skewed tile

    const int lane = threadIdx.x;
    const int bid  = blockIdx.x;
    const int b  = bid / (FF * NSP);
    const int r  = bid % (FF * NSP);
    const int f  = r / NSP;
    const int sp = r % NSP;
    const int t0 = sp * SPAN;

    // Lane-uniform coefficients -> scalar registers.
    const float inv_a0 = 1.0f / as_[f * KK];
    float bcf[KK], acf[ORD];
#pragma unroll
    for (int j = 0; j < KK; ++j) bcf[j] = bs[f * KK + j] * inv_a0;
#pragma unroll
    for (int j = 0; j < ORD; ++j) acf[j] = as_[f * KK + 1 + j] * inv_a0;

    const float* __restrict__ xrow = x + b * TT;

    // Stage x[t0-128, t0+4096) into skewed tile, coalesced float4 loads.
    // Zero-fill t<0 (zero input keeps zero state -> exact head).
#pragma unroll
    for (int i = 0; i < (NP4 + BLK - 1) / BLK; ++i) {   // 17
        const int p = i * BLK + lane;
        if (p < NP4) {
            const int t = t0 - WARM + 4 * p;
            float4 v = make_float4(0.f, 0.f, 0.f, 0.f);
            if (t >= 0) v = *reinterpret_cast<const float4*>(xrow + t);
            float* dst = lx + 65 * (p >> 4) + 4 * (p & 15);
            dst[0] = v.x; dst[1] = v.y; dst[2] = v.z; dst[3] = v.w;
        }
    }
    __syncthreads();   // single-wave block: cheap

    float st[ORD];
#pragma unroll
    for (int j = 0; j < ORD; ++j) st[j] = 0.0f;

    // Warm-up: groups q = lane, lane+1 (128 discarded steps).
    {
        const float* g0 = lx + 65 * lane;
#pragma unroll
        for (int s = 0; s < 64; ++s) iir_step(g0[s], st, bcf, acf);
        const float* g1 = lx + 65 * (lane + 1);
#pragma unroll
        for (int s = 0; s < 64; ++s) iir_step(g1[s], st, bcf, acf);
    }

    // Output: group q = lane+2, overwritten in place (lane-private now).
    {
        float* g2 = lx + 65 * (lane + 2);
#pragma unroll
        for (int s = 0; s < 64; ++s)
            g2[s] = iir_step(g2[s], st, bcf, acf);
    }
    __syncthreads();

    // Flush: 1024 float4 in t-order; each instruction stores 64 lanes x
    // 16B = 1KB contiguous; whole block = 16KB sequential.
    float* __restrict__ obase = out + (b * FF + f) * TT + t0;
#pragma unroll
    for (int i = 0; i < (SPAN / 4) / BLK; ++i) {        // 16
        const int p = i * BLK + lane;
        const float* src = lx + 65 * ((p >> 4) + 2) + 4 * (p & 15);
        float4 v;
        v.x = src[0]; v.y = src[1]; v.z = src[2]; v.w = src[3];
        *reinterpret_cast<float4*>(obase + 4 * p) = v;
    }
}

extern "C" void kernel_launch(void* const* d_in, const int* in_sizes, int n_in,
                              void* d_out, int out_size, void* d_ws,
                              size_t ws_size, hipStream_t stream) {
    const float* x   = (const float*)d_in[0];
    const float* bs  = (const float*)d_in[1];
    const float* as_ = (const float*)d_in[2];
    float* out = (float*)d_out;

    const int grid = BB * FF * NSP;  // 3840 single-wave blocks
    hipLaunchKernelGGL(iir_skew_kernel, dim3(grid), dim3(BLK), 0, stream,
                       x, bs, as_, out);
}

// Round 13
// 27.890 us; speedup vs baseline: 1.7232x; 1.2936x over previous
//
#include <hip/hip_runtime.h>

// IIR filter bank: B=16, T=32768, F=30, order 6 (K=7).
// Overlap-and-discard chunking (CHUNK=64, WARM=128).
// R12 = R9 structure (f-parallel lanes, LDS x tile, merged flush) +
//   FULL REGISTER STAGING of each lane's 192-sample window (48 float4,
//   three 16-read batches -> one lgkmcnt wait each), then 192 pure-FMA
//   steps with zero memory stalls.
//   Evidence: R11 counters showed VALUBusy 35%, VGPR=68 -> compiler reads
//   x just-in-time, ~120cy LDS stall every few samples, only ~2.25
//   waves/SIMD (LDS-capped) to cover. Time ~ VALU-work / VALUBusy in every
//   round; raising per-wave duty is the one untested lever.

#define BB 16
#define TT 32768
#define FF 30
#define KK 7
#define ORD 6
#define CHUNK 64
#define WARM 128
#define CPB 2                  // chunks per block
#define TSPAN (CPB * CHUNK)    // 128 samples per block
#define NBC (TT / TSPAN)       // 256 block-columns per row
#define YSTR 132               // row stride (528B, 16B-aligned)
#define XTILE (WARM + TSPAN)   // 256 floats staged x
#define BLK 64                 // ONE wave per block

// Transposed direct-form II step: 13 FMAs, no state shifting.
__device__ __forceinline__ float iir_step(float xv, float st[ORD],
                                          const float bcf[KK],
                                          const float acf[ORD]) {
    float y = fmaf(bcf[0], xv, st[0]);
#pragma unroll
    for (int j = 0; j < ORD - 1; ++j)
        st[j] = fmaf(-acf[j], y, fmaf(bcf[j + 1], xv, st[j + 1]));
    st[ORD - 1] = fmaf(-acf[ORD - 1], y, bcf[KK - 1] * xv);
    return y;
}

__global__ __launch_bounds__(BLK) void iir_reg_kernel(
    const float* __restrict__ x,    // [B][T]
    const float* __restrict__ bs,   // [F][K]
    const float* __restrict__ as_,  // [F][K]
    float* __restrict__ out)        // [B][F][T]
{
    __shared__ __align__(16) float ly[FF * YSTR];   // 15840 B output tile
    __shared__ __align__(16) float lx[XTILE];       //  1024 B x tile

    const int tid = threadIdx.x;
    const int b   = blockIdx.x / NBC;
    const int bc  = blockIdx.x % NBC;
    const int bt0 = bc * TSPAN;
    const int xs  = bt0 - WARM;     // negative only for bc==0

    const int f  = tid % FF;        // lanes 0-29: cl=0, 30-59: cl=1
    const int cl = tid / FF;
    const bool active = tid < FF * CPB;

    // Lane-uniform-per-f coefficients (latency overlaps x staging below).
    float bcf[KK], acf[ORD];
    {
        const int fc = active ? f : 0;
        const float inv_a0 = 1.0f / as_[fc * KK];
#pragma unroll
        for (int j = 0; j < KK; ++j) bcf[j] = bs[fc * KK + j] * inv_a0;
#pragma unroll
        for (int j = 0; j < ORD; ++j) acf[j] = as_[fc * KK + 1 + j] * inv_a0;
    }

    // Cooperative x stage: one float4 per lane; zero-fill t<0 (zero input
    // keeps zero state -> exact head).
    {
        const float* __restrict__ xrow = x + b * TT;
        const int t = xs + 4 * tid;
        float4 v = make_float4(0.f, 0.f, 0.f, 0.f);
        if (t >= 0) v = *reinterpret_cast<const float4*>(xrow + t);
        *reinterpret_cast<float4*>(lx + 4 * tid) = v;
    }
    __syncthreads();   // single-wave block: cheap

    if (active) {
        // Register-stage the lane's whole window: 48 float4 up front.
        // Each read has only 2 distinct addresses across the wave
        // (cl groups) -> broadcast + 2-way alias = free.
        const float4* lx4 = reinterpret_cast<const float4*>(lx);
        const int g0 = 16 * cl;             // window start (float4 units)
        float4 va[16], vb[16], vc[16];
#pragma unroll
        for (int k = 0; k < 16; ++k) va[k] = lx4[g0 + k];
#pragma unroll
        for (int k = 0; k < 16; ++k) vb[k] = lx4[g0 + 16 + k];
#pragma unroll
        for (int k = 0; k < 16; ++k) vc[k] = lx4[g0 + 32 + k];

        float st[ORD];
#pragma unroll
        for (int j = 0; j < ORD; ++j) st[j] = 0.0f;

        // Warm-up: 128 steps from registers, zero memory stalls.
#pragma unroll
        for (int k = 0; k < 16; ++k) {
            iir_step(va[k].x, st, bcf, acf);
            iir_step(va[k].y, st, bcf, acf);
            iir_step(va[k].z, st, bcf, acf);
            iir_step(va[k].w, st, bcf, acf);
        }
#pragma unroll
        for (int k = 0; k < 16; ++k) {
            iir_step(vb[k].x, st, bcf, acf);
            iir_step(vb[k].y, st, bcf, acf);
            iir_step(vb[k].z, st, bcf, acf);
            iir_step(vb[k].w, st, bcf, acf);
        }

        // Output: 64 steps, one ds_write_b128 per 4.
        float* lyc = ly + f * YSTR + cl * CHUNK;
#pragma unroll
        for (int k = 0; k < 16; ++k) {
            float4 y;
            y.x = iir_step(vc[k].x, st, bcf, acf);
            y.y = iir_step(vc[k].y, st, bcf, acf);
            y.z = iir_step(vc[k].z, st, bcf, acf);
            y.w = iir_step(vc[k].w, st, bcf, acf);
            *reinterpret_cast<float4*>(lyc + 4 * k) = y;
        }
    }
    __syncthreads();

    // Flush: 30 rows x 128 floats = 960 float4, 15 per lane; lanes 0-31
    // cover row 2it, lanes 32-63 row 2it+1 -> two contiguous 512B runs
    // per instruction, full 64B lines only.
    float* __restrict__ obase = out + b * FF * TT + bt0;
#pragma unroll
    for (int it = 0; it < (FF * TSPAN / 4) / BLK; ++it) {  // 15
        const int j  = tid + BLK * it;
        const int fr = j >> 5;            // 32 float4 per row
        const int tl = (j & 31) << 2;
        const float4 v = *reinterpret_cast<const float4*>(ly + fr * YSTR + tl);
        *reinterpret_cast<float4*>(obase + fr * TT + tl) = v;
    }
}

extern "C" void kernel_launch(void* const* d_in, const int* in_sizes, int n_in,
                              void* d_out, int out_size, void* d_ws,
                              size_t ws_size, hipStream_t stream) {
    const float* x   = (const float*)d_in[0];
    const float* bs  = (const float*)d_in[1];
    const float* as_ = (const float*)d_in[2];
    float* out = (float*)d_out;

    const int grid = BB * NBC;  // 4096 single-wave blocks
    hipLaunchKernelGGL(iir_reg_kernel, dim3(grid), dim3(BLK), 0, stream,
                       x, bs, as_, out);
}